// Round 13
// baseline (66.340 us; speedup 1.0000x reference)
//
#include <hip/hip_runtime.h>

#define B_ 32
#define C_ 64          // Cin = Cout
#define H_ 112
#define W_ 112
#define HW (H_ * W_)
#define HTILES 56            // 2-row tiles per image
#define NBLKC (B_ * HTILES)  // 1792, %8==0 for XCD swizzle

#define SLOTS 114            // slot = w+1; slots 0,113 are zeros
#define CHUNK 128            // bytes per (h,slot): 64 cin bf16
#define XROWB (SLOTS * CHUNK)              // 14592 B per (b,h)
#define XT_BYTES ((size_t)B_ * H_ * XROWB) // ~52.3 MB
#define WQ_OFF 131072

typedef short bf16x8 __attribute__((ext_vector_type(8)));
typedef float f32x4 __attribute__((ext_vector_type(4)));
typedef unsigned int u32;

#define GLOAD_LDS(g, l, sz)                                                   \
    __builtin_amdgcn_global_load_lds(                                         \
        (const __attribute__((address_space(1))) u32*)(const void*)(g),       \
        (__attribute__((address_space(3))) u32*)(void*)(l), (sz), 0, 0)

__device__ inline unsigned short f2bf(float f) {
    union { float f; unsigned u; } v;
    v.f = f;
    unsigned u = v.u;
    u += 0x7fffu + ((u >> 16) & 1u);   // RNE
    return (unsigned short)(u >> 16);
}

// ---------------------------------------------------------------------------
// Transform (VERIFIED r4-r12, HBM floor): x[b][c][h][w] fp32 ->
// xt[b][h][slot][cin] bf16; dword for cin-pair cp at (cp*4)^((slot&7)<<4)
// inside each 128-B chunk. Blocks 0..17 also pre-pack weights into wq2
// (verified r10): wq2[mw][t][lane] 16-B entries, t=(shift*2+c0)*2+m.
// ---------------------------------------------------------------------------
__global__ __launch_bounds__(256) void xform(const float* __restrict__ x,
                                             unsigned short* __restrict__ xt,
                                             const float* __restrict__ w,
                                             unsigned short* __restrict__ wq2) {
    __shared__ unsigned short pl[C_ * SLOTS];

    const int tid = threadIdx.x;
    const int b   = blockIdx.x / H_;
    const int h   = blockIdx.x % H_;

#pragma unroll
    for (int it = 0; it < 7; ++it) {
        const int u  = tid + 256 * it;        // < 1792 = 64c * 28 quads
        const int c  = u / 28;
        const int w4 = u % 28;
        const f32x4 v =
            *(const f32x4*)(x + ((size_t)(b * C_ + c) * H_ + h) * W_ + w4 * 4);
        const u32 lo = (u32)f2bf(v[0]) | ((u32)f2bf(v[1]) << 16);
        const u32 hi = (u32)f2bf(v[2]) | ((u32)f2bf(v[3]) << 16);
        u32* p = (u32*)&pl[c * SLOTS + w4 * 4];
        p[0] = lo;
        p[1] = hi;
    }
    __syncthreads();

    unsigned short* xtrow = xt + (size_t)(b * H_ + h) * (XROWB / 2);
#pragma unroll
    for (int it = 0; it < 15; ++it) {
        const int u = tid + 256 * it;         // < 3648 = 114 slots * 32 cps
        if (u < SLOTS * 32) {
            const int slot = u >> 5;
            const int cp   = u & 31;
            u32 val = 0;
            if (1 <= slot && slot <= 112) {
                const int ww = slot - 1;
                val = (u32)pl[(2 * cp) * SLOTS + ww] |
                      ((u32)pl[(2 * cp + 1) * SLOTS + ww] << 16);
            }
            *(u32*)((char*)xtrow + slot * CHUNK +
                    ((cp * 4) ^ ((slot & 7) << 4))) = val;
        }
    }

    // ---- folded weight quantize + per-wave prepack (verified r10) ----
    if (blockIdx.x < 18) {
        const int i = blockIdx.x * 256 + tid;   // < 4608 = 2*36*64
        const int lane = i & 63;
        const int t    = (i >> 6) % 36;
        const int mw   = i / 2304;
        const int shift = t >> 2;
        const int c0    = (t >> 1) & 1;
        const int m     = t & 1;
        const int dh = shift / 3, dw = shift % 3;
        const int lcol = lane & 15, kg = lane >> 4;
        const int cout = mw * 32 + m * 16 + lcol;
        const int cinb = c0 * 32 + kg * 8;
        bf16x8 pv;
#pragma unroll
        for (int j = 0; j < 8; ++j) {
            const float v = w[((cout * C_ + cinb + j) * 3 + dh) * 3 + dw];
            pv[j] = (v > 0.f) ? (short)0x3F80
                              : ((v < 0.f) ? (short)(unsigned short)0xBF80
                                           : (short)0);
        }
        *(bf16x8*)((char*)wq2 + ((size_t)(mw * 36 + t) * 64 + lane) * 16) = pv;
    }
}

// ---------------------------------------------------------------------------
// Conv implicit GEMM = r10 verified structure + LDS-repack epilogue.
// Block = (b, 2 output rows); waves 2x2 (mw: cout half, nw: row).
// Weights register-resident (wt[36]); K-loop = pure {ds_read_b128 -> 2 MFMA}.
// NEW: epilogue reuses xs (post-barrier) to repack acc into output-linear
// order, then streams xs -> out as dense float4 stores (14/thread, full
// 448-B runs) instead of 56 scalar stores scattering 64-B segments.
// ---------------------------------------------------------------------------
__global__ __launch_bounds__(256, 2) void conv_mfma(
    const unsigned short* __restrict__ xt, const unsigned short* __restrict__ wq2,
    const float* __restrict__ bias, const float* __restrict__ scale,
    float* __restrict__ out) {
    __shared__ char xs[4 * XROWB];   // 58368 B; epilogue reuses 57344 B

    const int tid  = threadIdx.x;
    const int lane = tid & 63;
    const int wave = tid >> 6;
    const int lcol = lane & 15;
    const int kg   = lane >> 4;
    const int mw   = wave >> 1;      // cout half
    const int nw   = wave & 1;       // row within tile

    const int bid = blockIdx.x;
    const int s   = (bid & 7) * (NBLKC / 8) + (bid >> 3);   // XCD-bijective
    const int b   = s / HTILES;
    const int h0  = (s % HTILES) * 2;

    const char* xtc = (const char*)xt + (size_t)b * H_ * XROWB;

    // ---- preload all 36 weight tiles for this wave (coalesced, L2) ----
    bf16x8 wt[36];
    {
        const char* wp = (const char*)wq2 + (size_t)mw * 36 * 1024 + lane * 16;
#pragma unroll
        for (int t = 0; t < 36; ++t) wt[t] = *(const bf16x8*)(wp + t * 1024);
    }

    // ---- stage: wave r copies xt row h0-1+r linearly into LDS ----
    {
        const int r    = wave;
        const int xrow = h0 - 1 + r;
        char* dst = xs + r * XROWB;
        if (0 <= xrow && xrow < H_) {
            const char* src = xtc + (size_t)xrow * XROWB + lane * 16;
#pragma unroll
            for (int ch = 0; ch < 14; ++ch)
                GLOAD_LDS(src + ch * 1024, dst + ch * 1024, 16);
            GLOAD_LDS(xtc + (size_t)xrow * XROWB + 14336 + lane * 4,
                      dst + 14336, 4);
        } else {
            char* d = dst + lane * 16;
            const f32x4 z = {0.f, 0.f, 0.f, 0.f};
#pragma unroll
            for (int ch = 0; ch < 14; ++ch) *(f32x4*)(d + ch * 1024) = z;
            *(u32*)(dst + 14336 + lane * 4) = 0u;
        }
    }

    // scale/bias loads issued early (L2-hot after first blocks)
    const float sc = scale[0];
    f32x4 bs[2];
#pragma unroll
    for (int m = 0; m < 2; ++m)
        bs[m] = *(const f32x4*)(bias + mw * 32 + m * 16 + kg * 4);

    __syncthreads();

    // swizzle-adjusted K-offsets (verified r4)
    int koff[3][2];
#pragma unroll
    for (int dw = 0; dw < 3; ++dw) {
        const int key = ((lcol + dw) & 7) << 4;
        koff[dw][0] = (kg * 16) ^ key;
        koff[dw][1] = (64 + kg * 16) ^ key;
    }

    f32x4 acc[2][7];
#pragma unroll
    for (int m = 0; m < 2; ++m)
#pragma unroll
        for (int nf = 0; nf < 7; ++nf) acc[m][nf] = (f32x4){0.f, 0.f, 0.f, 0.f};

#pragma unroll
    for (int dh = 0; dh < 3; ++dh) {
        const char* rowb = xs + (nw + dh) * XROWB;
#pragma unroll
        for (int dw = 0; dw < 3; ++dw) {
            const char* colb = rowb + (lcol + dw) * CHUNK;
#pragma unroll
            for (int c0 = 0; c0 < 2; ++c0) {
                const int t0 = ((dh * 3 + dw) * 2 + c0) * 2;   // wt index
                const char* cb = colb + koff[dw][c0];
#pragma unroll
                for (int nf = 0; nf < 7; ++nf) {
                    const bf16x8 bv = *(const bf16x8*)(cb + nf * 2048);
                    acc[0][nf] = __builtin_amdgcn_mfma_f32_16x16x32_bf16(
                        wt[t0 + 0], bv, acc[0][nf], 0, 0, 0);
                    acc[1][nf] = __builtin_amdgcn_mfma_f32_16x16x32_bf16(
                        wt[t0 + 1], bv, acc[1][nf], 0, 0, 0);
                }
            }
        }
    }

    __syncthreads();   // all waves done reading xs B-frags

    // ---- repack: acc -> xs in output-linear order ----
    // L(cout,hsub,col) = ((cout*2 + hsub)*112 + col) floats; total 14336 f.
    {
        float* xf = (float*)xs;
#pragma unroll
        for (int m = 0; m < 2; ++m) {
#pragma unroll
            for (int nf = 0; nf < 7; ++nf) {
                const int col = nf * 16 + lcol;
#pragma unroll
                for (int rr = 0; rr < 4; ++rr) {
                    const int cout = mw * 32 + m * 16 + kg * 4 + rr;
                    xf[(cout * 2 + nw) * 112 + col] =
                        sc * (acc[m][nf][rr] + bs[m][rr]);
                }
            }
        }
    }
    __syncthreads();

    // ---- coalesced stream xs -> out: 14 x float4 per thread ----
    {
        const float* xf = (const float*)xs;
        float* outb = out + (size_t)b * C_ * HW + (size_t)h0 * W_;
#pragma unroll
        for (int it = 0; it < 14; ++it) {
            const int u    = it * 256 + tid;    // chunk index, < 3584
            const int L    = u * 4;             // float index
            const int cout = L / 224;           // 224 floats per cout
            const int rem  = L % 224;
            const int hsub = rem / 112;
            const int colf = rem % 112;
            const f32x4 v = *(const f32x4*)(xf + L);
            *(f32x4*)(outb + (size_t)cout * HW + hsub * W_ + colf) = v;
        }
    }
}

extern "C" void kernel_launch(void* const* d_in, const int* in_sizes, int n_in,
                              void* d_out, int out_size, void* d_ws,
                              size_t ws_size, hipStream_t stream) {
    const float* x     = (const float*)d_in[0];
    const float* w     = (const float*)d_in[1];
    const float* bias  = (const float*)d_in[2];
    const float* scale = (const float*)d_in[3];
    float* out         = (float*)d_out;

    unsigned short* wq2 = (unsigned short*)d_ws;  // 73728 B prepacked weights
    unsigned short* xt  = (unsigned short*)((char*)d_ws + WQ_OFF);

    xform<<<B_ * H_, 256, 0, stream>>>(x, xt, w, wq2);
    conv_mfma<<<NBLKC, 256, 0, stream>>>(xt, wq2, bias, scale, out);
}

// Round 14
// 64.637 us; speedup vs baseline: 1.0263x; 1.0263x over previous
//
#include <hip/hip_runtime.h>

#define B_ 32
#define C_ 64          // Cin = Cout
#define H_ 112
#define W_ 112
#define HW (H_ * W_)
#define HTILES 56            // 2-row tiles per image
#define NBLKC (B_ * HTILES)  // 1792, %8==0 for XCD swizzle

#define SLOTS 114            // slot = w+1; slots 0,113 are zeros
#define CHUNK 128            // bytes per (h,slot): 64 cin bf16
#define XROWB (SLOTS * CHUNK)              // 14592 B per (b,h)
#define XT_BYTES ((size_t)B_ * H_ * XROWB) // ~52.3 MB
#define WQ_OFF 131072

typedef short bf16x8 __attribute__((ext_vector_type(8)));
typedef float f32x4 __attribute__((ext_vector_type(4)));
typedef unsigned int u32;

#define GLOAD_LDS(g, l, sz)                                                   \
    __builtin_amdgcn_global_load_lds(                                         \
        (const __attribute__((address_space(1))) u32*)(const void*)(g),       \
        (__attribute__((address_space(3))) u32*)(void*)(l), (sz), 0, 0)

__device__ inline unsigned short f2bf(float f) {
    union { float f; unsigned u; } v;
    v.f = f;
    unsigned u = v.u;
    u += 0x7fffu + ((u >> 16) & 1u);   // RNE
    return (unsigned short)(u >> 16);
}

// ---------------------------------------------------------------------------
// Transform (VERIFIED r4-r13, HBM floor ~25.5 us): x[b][c][h][w] fp32 ->
// xt[b][h][slot][cin] bf16; dword for cin-pair cp at (cp*4)^((slot&7)<<4)
// inside each 128-B chunk.
// Blocks 0..17 additionally pre-pack quantized weights into wq2:
// wq2[mw][t][lane] 16-B entries, t=(shift*2+c0)*2+m, matching the conv
// K-loop's A-fragment consumption order. Tile loads are 1-KB coalesced.
// ---------------------------------------------------------------------------
__global__ __launch_bounds__(256) void xform(const float* __restrict__ x,
                                             unsigned short* __restrict__ xt,
                                             const float* __restrict__ w,
                                             unsigned short* __restrict__ wq2) {
    __shared__ unsigned short pl[C_ * SLOTS];

    const int tid = threadIdx.x;
    const int b   = blockIdx.x / H_;
    const int h   = blockIdx.x % H_;

#pragma unroll
    for (int it = 0; it < 7; ++it) {
        const int u  = tid + 256 * it;        // < 1792 = 64c * 28 quads
        const int c  = u / 28;
        const int w4 = u % 28;
        const f32x4 v =
            *(const f32x4*)(x + ((size_t)(b * C_ + c) * H_ + h) * W_ + w4 * 4);
        const u32 lo = (u32)f2bf(v[0]) | ((u32)f2bf(v[1]) << 16);
        const u32 hi = (u32)f2bf(v[2]) | ((u32)f2bf(v[3]) << 16);
        u32* p = (u32*)&pl[c * SLOTS + w4 * 4];
        p[0] = lo;
        p[1] = hi;
    }
    __syncthreads();

    unsigned short* xtrow = xt + (size_t)(b * H_ + h) * (XROWB / 2);
#pragma unroll
    for (int it = 0; it < 15; ++it) {
        const int u = tid + 256 * it;         // < 3648 = 114 slots * 32 cps
        if (u < SLOTS * 32) {
            const int slot = u >> 5;
            const int cp   = u & 31;
            u32 val = 0;
            if (1 <= slot && slot <= 112) {
                const int ww = slot - 1;
                val = (u32)pl[(2 * cp) * SLOTS + ww] |
                      ((u32)pl[(2 * cp + 1) * SLOTS + ww] << 16);
            }
            *(u32*)((char*)xtrow + slot * CHUNK +
                    ((cp * 4) ^ ((slot & 7) << 4))) = val;
        }
    }

    // ---- folded weight quantize + per-wave prepack (4608 threads) ----
    if (blockIdx.x < 18) {
        const int i = blockIdx.x * 256 + tid;   // < 4608 = 2*36*64
        const int lane = i & 63;
        const int t    = (i >> 6) % 36;
        const int mw   = i / 2304;
        const int shift = t >> 2;
        const int c0    = (t >> 1) & 1;
        const int m     = t & 1;
        const int dh = shift / 3, dw = shift % 3;
        const int lcol = lane & 15, kg = lane >> 4;
        const int cout = mw * 32 + m * 16 + lcol;
        const int cinb = c0 * 32 + kg * 8;
        unsigned short pk[8];
#pragma unroll
        for (int j = 0; j < 8; ++j) {
            const float v = w[((cout * C_ + cinb + j) * 3 + dh) * 3 + dw];
            pk[j] = (v > 0.f) ? (unsigned short)0x3F80
                              : ((v < 0.f) ? (unsigned short)0xBF80
                                           : (unsigned short)0);
        }
        bf16x8 pv;
#pragma unroll
        for (int j = 0; j < 8; ++j) pv[j] = (short)pk[j];
        *(bf16x8*)((char*)wq2 + ((size_t)(mw * 36 + t) * 64 + lane) * 16) = pv;
    }
}

// ---------------------------------------------------------------------------
// Conv implicit GEMM = round-4 structure with REGISTER-RESIDENT weights.
// Block = (b, 2 output rows); waves 2x2 (mw: cout half, nw: row).
// Wave preloads its 36 A-tiles (576 B/lane = 144 VGPRs) from wq2 before the
// barrier; the K-loop is then pure {ds_read_b128 -> 2 MFMA} with ZERO global
// loads on the critical path (r6/r9 lesson). launch_bounds(256,2): 256 VGPRs.
// Measured best: r10 63.7 us total, reproduced r12 65.3 us.
// Failed alternatives (do not retry): r5 persistent ring (VGPR 200, occ 9%),
// r6 global edge B-frags (+40 us), r7 cin-split (swizzle conflicts + spill),
// r8 padded-N (acc spill: WRITE 226 MB), r9 F=4 global A-tiles (+31 us),
// r11 w-split pipeline (+2 us), r13 LDS-repack stores (+2.6 us).
// ---------------------------------------------------------------------------
__global__ __launch_bounds__(256, 2) void conv_mfma(
    const unsigned short* __restrict__ xt, const unsigned short* __restrict__ wq2,
    const float* __restrict__ bias, const float* __restrict__ scale,
    float* __restrict__ out) {
    __shared__ char xs[4 * XROWB];   // 58368 B -> 2 blocks/CU

    const int tid  = threadIdx.x;
    const int lane = tid & 63;
    const int wave = tid >> 6;
    const int lcol = lane & 15;
    const int kg   = lane >> 4;
    const int mw   = wave >> 1;      // cout half
    const int nw   = wave & 1;       // row within tile

    const int bid = blockIdx.x;
    const int s   = (bid & 7) * (NBLKC / 8) + (bid >> 3);   // XCD-bijective
    const int b   = s / HTILES;
    const int h0  = (s % HTILES) * 2;

    const char* xtc = (const char*)xt + (size_t)b * H_ * XROWB;

    // ---- preload all 36 weight tiles for this wave (coalesced, L2) ----
    bf16x8 wt[36];
    {
        const char* wp = (const char*)wq2 + (size_t)mw * 36 * 1024 + lane * 16;
#pragma unroll
        for (int t = 0; t < 36; ++t) wt[t] = *(const bf16x8*)(wp + t * 1024);
    }

    // ---- stage: wave r copies xt row h0-1+r linearly into LDS ----
    {
        const int r    = wave;
        const int xrow = h0 - 1 + r;
        char* dst = xs + r * XROWB;
        if (0 <= xrow && xrow < H_) {
            const char* src = xtc + (size_t)xrow * XROWB + lane * 16;
#pragma unroll
            for (int ch = 0; ch < 14; ++ch)
                GLOAD_LDS(src + ch * 1024, dst + ch * 1024, 16);
            GLOAD_LDS(xtc + (size_t)xrow * XROWB + 14336 + lane * 4,
                      dst + 14336, 4);
        } else {
            char* d = dst + lane * 16;
            const f32x4 z = {0.f, 0.f, 0.f, 0.f};
#pragma unroll
            for (int ch = 0; ch < 14; ++ch) *(f32x4*)(d + ch * 1024) = z;
            *(u32*)(dst + 14336 + lane * 4) = 0u;
        }
    }
    __syncthreads();

    // swizzle-adjusted K-offsets (verified r4)
    int koff[3][2];
#pragma unroll
    for (int dw = 0; dw < 3; ++dw) {
        const int key = ((lcol + dw) & 7) << 4;
        koff[dw][0] = (kg * 16) ^ key;
        koff[dw][1] = (64 + kg * 16) ^ key;
    }

    f32x4 acc[2][7];
#pragma unroll
    for (int m = 0; m < 2; ++m)
#pragma unroll
        for (int nf = 0; nf < 7; ++nf) acc[m][nf] = (f32x4){0.f, 0.f, 0.f, 0.f};

#pragma unroll
    for (int dh = 0; dh < 3; ++dh) {
        const char* rowb = xs + (nw + dh) * XROWB;
#pragma unroll
        for (int dw = 0; dw < 3; ++dw) {
            const char* colb = rowb + (lcol + dw) * CHUNK;
#pragma unroll
            for (int c0 = 0; c0 < 2; ++c0) {
                const int t0 = ((dh * 3 + dw) * 2 + c0) * 2;   // wt index
                const char* cb = colb + koff[dw][c0];
#pragma unroll
                for (int nf = 0; nf < 7; ++nf) {
                    const bf16x8 bv = *(const bf16x8*)(cb + nf * 2048);
                    acc[0][nf] = __builtin_amdgcn_mfma_f32_16x16x32_bf16(
                        wt[t0 + 0], bv, acc[0][nf], 0, 0, 0);
                    acc[1][nf] = __builtin_amdgcn_mfma_f32_16x16x32_bf16(
                        wt[t0 + 1], bv, acc[1][nf], 0, 0, 0);
                }
            }
        }
    }

    // ---- epilogue ----
    const float sc = scale[0];
    const int h = h0 + nw;
#pragma unroll
    for (int m = 0; m < 2; ++m) {
        const int cobase = mw * 32 + m * 16 + kg * 4;
        const f32x4 bs = *(const f32x4*)(bias + cobase);
#pragma unroll
        for (int nf = 0; nf < 7; ++nf) {
            const int col = nf * 16 + lcol;
#pragma unroll
            for (int rr = 0; rr < 4; ++rr)
                out[((size_t)(b * C_ + cobase + rr)) * HW + h * W_ + col] =
                    sc * (acc[m][nf][rr] + bs[rr]);
        }
    }
}

extern "C" void kernel_launch(void* const* d_in, const int* in_sizes, int n_in,
                              void* d_out, int out_size, void* d_ws,
                              size_t ws_size, hipStream_t stream) {
    const float* x     = (const float*)d_in[0];
    const float* w     = (const float*)d_in[1];
    const float* bias  = (const float*)d_in[2];
    const float* scale = (const float*)d_in[3];
    float* out         = (float*)d_out;

    unsigned short* wq2 = (unsigned short*)d_ws;  // 73728 B prepacked weights
    unsigned short* xt  = (unsigned short*)((char*)d_ws + WQ_OFF);

    xform<<<B_ * H_, 256, 0, stream>>>(x, xt, w, wq2);
    conv_mfma<<<NBLKC, 256, 0, stream>>>(xt, wq2, bias, scale, out);
}